// Round 12
// baseline (150.785 us; speedup 1.0000x reference)
//
#include <hip/hip_runtime.h>
#include <math.h>
#include <stdint.h>

// EKF batch step, N independent 5-state filters.
// Exploits A rows 3,4 == 0 => P_ has zero cross blocks, S diagonal,
// K has only 2 nonzeros.
//
// R12: 4 tiles per wave, hand-unrolled, named-scalar ping-pong.
// Cross-round invariant: every non-persistent variant with ~7800 waves ran
// ~47us regardless of internals (R2: 7813 waves / 47.4us = 165 waves/us) =>
// front-end wave-launch rate ceiling, not memory. Fix: 1954 one-wave blocks,
// each wave does 4 tiles (launch floor ~12us). Inputs load straight to
// registers (only the used 3x3 P block; R7-validated); LDS only for the
// output transpose. No structs/refs/lambdas (R8-R10 scratch lesson): two
// named 16-float register sets, macro-unrolled L/P schedule gives 2-deep
// load pipelining in pure SSA.

#define BLK 64
#define TPW 4   // tiles per wave

#define DECL(p) \
    float p##_p00, p##_p01, p##_p02, p##_p10, p##_p11, p##_p12, \
          p##_p20, p##_p21, p##_p22, p##_x0, p##_x1, p##_x2, \
          p##_a0, p##_a1, p##_y0, p##_y1

#define LOAD(p, tile_) do { \
    const int b_ = (tile_) * BLK; \
    const float* pb_ = Pg + (size_t)(b_ + l) * 25; \
    float3 r0_ = *(const float3*)(pb_); \
    float3 r1_ = *(const float3*)(pb_ + 5); \
    float3 r2_ = *(const float3*)(pb_ + 10); \
    float3 xv_ = *(const float3*)(xg + (size_t)(b_ + l) * 5); \
    float2 av_ = *(const float2*)(ag + (size_t)(b_ + l) * 2); \
    p##_p00 = r0_.x; p##_p01 = r0_.y; p##_p02 = r0_.z; \
    p##_p10 = r1_.x; p##_p11 = r1_.y; p##_p12 = r1_.z; \
    p##_p20 = r2_.x; p##_p21 = r2_.y; p##_p22 = r2_.z; \
    p##_x0 = xv_.x; p##_x1 = xv_.y; p##_x2 = xv_.z; \
    p##_a0 = av_.x; p##_a1 = av_.y; \
    p##_y0 = Yg[b_ + l]; p##_y1 = Yg[N + b_ + l]; \
} while (0)

#define PROC(p, tile_) do { \
    const int b_ = (tile_) * BLK; \
    float vel = g0 * p##_a0, angvel = g1 * p##_a1; \
    float ar = p##_x2 + angvel * dt + fPI; \
    float wm = fmodf(ar, f2PI); if (wm < 0.f) wm += f2PI; \
    float ang = wm - fPI; \
    float sn, cs; sincosf(ang, &sn, &cs); \
    float px = fminf(fmaxf(p##_x0 + vel * cs * dt, -1.f), 1.f); \
    float py = fminf(fmaxf(p##_x1 + vel * sn * dt, -1.f), 1.f); \
    float m0 = -vel * sn * dt, m1 = vel * cs * dt; \
    float b00 = p##_p00 + m0 * p##_p20, b01 = p##_p01 + m0 * p##_p21, b02 = p##_p02 + m0 * p##_p22; \
    float b10 = p##_p10 + m1 * p##_p20, b11 = p##_p11 + m1 * p##_p21, b12 = p##_p12 + m1 * p##_p22; \
    float t00 = b00 + m0 * b02, t01 = b01 + m1 * b02; \
    float t10 = b10 + m0 * b12, t11 = b11 + m1 * b12; \
    float t20 = p##_p20 + m0 * p##_p22, t21 = p##_p21 + m1 * p##_p22, t22 = p##_p22; \
    float t02 = b02, t12 = b12; \
    t00 += q0; t11 += q1; t22 += q2; \
    float s01 = 0.5f * (t01 + t10), s02 = 0.5f * (t02 + t20), s12 = 0.5f * (t12 + t21); \
    t00 += EPS_; t11 += EPS_; t22 += EPS_; \
    float S00 = q3 * og0 * og0 + vel * vel * e2k0 + e2s0; \
    float S11 = q4 * og1 * og1 + angvel * angvel * e2k1 + e2s1; \
    float K30 = q3 * og0 / S00, K41 = q4 * og1 / S11; \
    float xn3 = vel    + K30 * (p##_y0 - og0 * vel); \
    float xn4 = angvel + K41 * (p##_y1 - og1 * angvel); \
    float Pn33 = (1.f - K30 * og0) * q3 + EPS_; \
    float Pn44 = (1.f - K41 * og1) * q4 + EPS_; \
    float* xx = s + l * 5; \
    xx[0] = px; xx[1] = py; xx[2] = ang; xx[3] = xn3; xx[4] = xn4; \
    float* pp = s + 320 + l * 25; \
    pp[0]  = t00; pp[1]  = s01; pp[2]  = s02; pp[3]  = 0.f; pp[4]  = 0.f; \
    pp[5]  = s01; pp[6]  = t11; pp[7]  = s12; pp[8]  = 0.f; pp[9]  = 0.f; \
    pp[10] = s02; pp[11] = s12; pp[12] = t22; pp[13] = 0.f; pp[14] = 0.f; \
    pp[15] = 0.f; pp[16] = 0.f; pp[17] = 0.f; pp[18] = Pn33; pp[19] = 0.f; \
    pp[20] = 0.f; pp[21] = 0.f; pp[22] = 0.f; pp[23] = 0.f; pp[24] = Pn44; \
    float* kk = s + 1920 + l * 10; \
    kk[0] = 0.f; kk[1] = 0.f; kk[2] = 0.f; kk[3] = 0.f; kk[4] = 0.f; \
    kk[5] = 0.f; kk[6] = K30; kk[7] = 0.f; kk[8] = 0.f; kk[9] = K41; \
    float4* gx4 = (float4*)(out + (size_t)b_ * 5); \
    float4* gp4 = (float4*)(out + (size_t)5 * N + (size_t)b_ * 25); \
    float4* gk4 = (float4*)(out + (size_t)30 * N + (size_t)b_ * 10); \
    const float4* lx4 = (const float4*)s; \
    const float4* lp4 = (const float4*)(s + 320); \
    const float4* lk4 = (const float4*)(s + 1920); \
    gx4[l] = lx4[l]; \
    if (l < 16) gx4[64 + l] = lx4[64 + l]; \
    gp4[0 * 64 + l] = lp4[0 * 64 + l]; gp4[1 * 64 + l] = lp4[1 * 64 + l]; \
    gp4[2 * 64 + l] = lp4[2 * 64 + l]; gp4[3 * 64 + l] = lp4[3 * 64 + l]; \
    gp4[4 * 64 + l] = lp4[4 * 64 + l]; gp4[5 * 64 + l] = lp4[5 * 64 + l]; \
    if (l < 16) gp4[384 + l] = lp4[384 + l]; \
    gk4[0 * 64 + l] = lk4[0 * 64 + l]; gk4[1 * 64 + l] = lk4[1 * 64 + l]; \
    if (l < 32) gk4[128 + l] = lk4[128 + l]; \
} while (0)

__global__ __launch_bounds__(64, 2) void ekf_kernel(
    const float* __restrict__ xg, const float* __restrict__ Pg,
    const float* __restrict__ ag, const float* __restrict__ Yg,
    const float* __restrict__ n1, const float* __restrict__ n2s,
    const float* __restrict__ n2k, const float* __restrict__ gains,
    const float* __restrict__ og, float* __restrict__ out, int N)
{
    // Output-transpose slice only: x 320 | P 1600 | K 640 = 2560 f = 10.25 KiB
    __shared__ float s[2560];
    const int l = threadIdx.x;
    const int w = blockIdx.x;
    const int tiles = (N + BLK - 1) / BLK;
    const int t0 = w * TPW;
    if (t0 >= tiles) return;

    const float dt = 0.1f;
    const float fPI  = 3.14159265358979323846f;
    const float f2PI = 6.28318530717958647692f;
    const float EPS_ = 1e-6f;

    // Uniform scalars (SGPR) + transcendentals, once per wave.
    const float g0 = gains[0], g1 = gains[1];
    const float og0 = og[0], og1 = og[1];
    const float q0 = expf(2.f * n1[0]), q1 = expf(2.f * n1[1]),
                q2 = expf(2.f * n1[2]), q3 = expf(2.f * n1[3]),
                q4 = expf(2.f * n1[4]);
    const float e2s0 = expf(2.f * n2s[0]), e2s1 = expf(2.f * n2s[1]);
    const float e2k0 = expf(2.f * n2k[0]), e2k1 = expf(2.f * n2k[1]);

    if ((t0 + TPW) * BLK <= N) {
        // All 4 tiles full: unrolled 2-deep pipelined schedule, pure SSA.
        DECL(A); DECL(B);
        LOAD(A, t0);
        LOAD(B, t0 + 1);
        PROC(A, t0);
        LOAD(A, t0 + 2);
        PROC(B, t0 + 1);
        LOAD(B, t0 + 3);
        PROC(A, t0 + 2);
        PROC(B, t0 + 3);
    } else {
        // Boundary wave (contains the global tail): guarded scalar path.
        for (int tt = 0; tt < TPW; ++tt) {
            const int tile = t0 + tt;
            if (tile >= tiles) break;
            const int i = tile * BLK + l;
            if (i >= N) continue;
            const float* pr = Pg + (size_t)i * 25;
            float p00 = pr[0],  p01 = pr[1],  p02 = pr[2];
            float p10 = pr[5],  p11 = pr[6],  p12 = pr[7];
            float p20 = pr[10], p21 = pr[11], p22 = pr[12];
            float x0 = xg[i * 5 + 0], x1 = xg[i * 5 + 1], x2 = xg[i * 5 + 2];
            float a0 = ag[i * 2 + 0], a1 = ag[i * 2 + 1];
            float y0 = Yg[i], y1 = Yg[N + i];

            float vel = g0 * a0, angvel = g1 * a1;
            float ar = x2 + angvel * dt + fPI;
            float wm = fmodf(ar, f2PI);
            if (wm < 0.f) wm += f2PI;
            float ang = wm - fPI;
            float sn, cs;
            sincosf(ang, &sn, &cs);
            float px = fminf(fmaxf(x0 + vel * cs * dt, -1.f), 1.f);
            float py = fminf(fmaxf(x1 + vel * sn * dt, -1.f), 1.f);
            float m0 = -vel * sn * dt, m1 = vel * cs * dt;
            float b00 = p00 + m0 * p20, b01 = p01 + m0 * p21, b02 = p02 + m0 * p22;
            float b10 = p10 + m1 * p20, b11 = p11 + m1 * p21, b12 = p12 + m1 * p22;
            float t00 = b00 + m0 * b02, t01 = b01 + m1 * b02;
            float t10 = b10 + m0 * b12, t11 = b11 + m1 * b12;
            float t20 = p20 + m0 * p22, t21 = p21 + m1 * p22, t22 = p22;
            float t02 = b02, t12 = b12;
            t00 += q0; t11 += q1; t22 += q2;
            float s01 = 0.5f * (t01 + t10);
            float s02 = 0.5f * (t02 + t20);
            float s12 = 0.5f * (t12 + t21);
            t00 += EPS_; t11 += EPS_; t22 += EPS_;
            float S00 = q3 * og0 * og0 + vel * vel * e2k0 + e2s0;
            float S11 = q4 * og1 * og1 + angvel * angvel * e2k1 + e2s1;
            float K30 = q3 * og0 / S00;
            float K41 = q4 * og1 / S11;
            float xn3 = vel    + K30 * (y0 - og0 * vel);
            float xn4 = angvel + K41 * (y1 - og1 * angvel);
            float Pn33 = (1.f - K30 * og0) * q3 + EPS_;
            float Pn44 = (1.f - K41 * og1) * q4 + EPS_;

            float* gx = out + (size_t)i * 5;
            gx[0] = px; gx[1] = py; gx[2] = ang; gx[3] = xn3; gx[4] = xn4;
            float* gp = out + (size_t)5 * N + (size_t)i * 25;
            gp[0] = t00; gp[1] = s01; gp[2] = s02; gp[3] = 0.f; gp[4] = 0.f;
            gp[5] = s01; gp[6] = t11; gp[7] = s12; gp[8] = 0.f; gp[9] = 0.f;
            gp[10] = s02; gp[11] = s12; gp[12] = t22; gp[13] = 0.f; gp[14] = 0.f;
            gp[15] = 0.f; gp[16] = 0.f; gp[17] = 0.f; gp[18] = Pn33; gp[19] = 0.f;
            gp[20] = 0.f; gp[21] = 0.f; gp[22] = 0.f; gp[23] = 0.f; gp[24] = Pn44;
            float* gk = out + (size_t)30 * N + (size_t)i * 10;
            gk[0] = 0.f; gk[1] = 0.f; gk[2] = 0.f; gk[3] = 0.f; gk[4] = 0.f;
            gk[5] = 0.f; gk[6] = K30; gk[7] = 0.f; gk[8] = 0.f; gk[9] = K41;
        }
    }
}

extern "C" void kernel_launch(void* const* d_in, const int* in_sizes, int n_in,
                              void* d_out, int out_size, void* d_ws, size_t ws_size,
                              hipStream_t stream) {
    const float* x     = (const float*)d_in[0];
    const float* P     = (const float*)d_in[1];
    const float* a     = (const float*)d_in[2];
    const float* Y     = (const float*)d_in[3];
    const float* n1    = (const float*)d_in[4];
    const float* n2s   = (const float*)d_in[5];
    const float* n2k   = (const float*)d_in[6];
    const float* gains = (const float*)d_in[7];
    const float* og    = (const float*)d_in[8];
    const int N = in_sizes[0] / 5;
    const int tiles = (N + BLK - 1) / BLK;
    const int G = (tiles + TPW - 1) / TPW;   // one wave per block, 4 tiles/wave
    ekf_kernel<<<G, 64, 0, stream>>>(x, P, a, Y, n1, n2s, n2k, gains, og,
                                     (float*)d_out, N);
}